// Round 1
// baseline (224.572 us; speedup 1.0000x reference)
//
#include <hip/hip_runtime.h>

#define BB 16
#define NN 256
#define DIN 32
#define DD 64
#define D2 128
#define RTOT 4096      // BB*NN rows
#define GB 256         // blocks for bc/d/e kernels
#define RPB 16         // rows per block

// x[r,c] = fea[r,:] @ encW + encb
__global__ __launch_bounds__(256) void enc_kernel(
    const float* __restrict__ fea, const float* __restrict__ W,
    const float* __restrict__ bias, float* __restrict__ x) {
  int g = blockIdx.x * 256 + threadIdx.x;   // 0 .. RTOT*DD-1
  int r = g >> 6, c = g & 63;
  const float* fr = fea + r * DIN;
  float acc = bias[c];
#pragma unroll
  for (int k = 0; k < DIN; ++k) acc = fmaf(fr[k], W[k * DD + c], acc);
  x[g] = acc;
}

// Per layer: agg (sparse over adj) -> h -> MLP1 -> h1 + BN1 partial stats
__global__ __launch_bounds__(256) void bc_kernel(
    const float* __restrict__ adj, const float* __restrict__ x,
    const float* __restrict__ bondW, const float* __restrict__ epsp,
    const float* __restrict__ W1, const float* __restrict__ b1,
    float* __restrict__ h1, float* __restrict__ p1s, float* __restrict__ p1q) {
  __shared__ float sW1[DD * D2];      // 32 KB
  __shared__ float sadj[RPB][NN];     // 16 KB
  __shared__ float sh[RPB][DD];       // 4 KB
  __shared__ float sred[256];
  int tid = threadIdx.x, bid = blockIdx.x;
  int lane = tid & 63, wv = tid >> 6;

  for (int i = tid; i < DD * D2; i += 256) sW1[i] = W1[i];
  {
    const float4* src = (const float4*)(adj + (size_t)bid * RPB * NN);
    float4* dst = (float4*)&sadj[0][0];
    for (int i = tid; i < RPB * NN / 4; i += 256) dst[i] = src[i];
  }
  __syncthreads();

  float bw = bondW[lane];
  float epv = 1.0f + epsp[0];
  // each wave handles 4 of the block's 16 rows; lane = output channel d
  for (int k = 0; k < 4; ++k) {
    int lr = k * 4 + wv;
    int r = bid * RPB + lr;
    const float* xb = x + (size_t)(r & ~(NN - 1)) * DD;  // batch base
    float acc = 0.f;
    for (int j4 = 0; j4 < NN; j4 += 4) {
      float4 a4 = *(const float4*)&sadj[lr][j4];
      float av[4] = {a4.x, a4.y, a4.z, a4.w};
#pragma unroll
      for (int u = 0; u < 4; ++u) {
        float a = av[u];
        if (a != 0.f) {               // wave-uniform branch
          float aa = fminf(a, 1.0f);
          float v = fmaf(aa, xb[(j4 + u) * DD + lane], a * bw);
          acc += fmaxf(v, 0.f);
        }
      }
    }
    sh[lr][lane] = fmaf(epv, x[(size_t)r * DD + lane], acc);
  }
  __syncthreads();

  // MLP1: thread = (channel c in [0,128), row-parity rl), 8 row-iters
  int c = tid & 127, rl = tid >> 7;
  float bc = b1[c];
  float ssum = 0.f, sq = 0.f;
  for (int rr = 0; rr < 8; ++rr) {
    int lr = rr * 2 + rl;
    float acc = bc;
#pragma unroll
    for (int d = 0; d < DD; ++d) acc = fmaf(sh[lr][d], sW1[d * D2 + c], acc);
    h1[(size_t)(bid * RPB + lr) * D2 + c] = acc;
    ssum += acc; sq = fmaf(acc, acc, sq);
  }
  sred[tid] = ssum; __syncthreads();
  if (tid < 128) p1s[bid * 128 + tid] = sred[tid] + sred[tid + 128];
  __syncthreads();
  sred[tid] = sq; __syncthreads();
  if (tid < 128) p1q[bid * 128 + tid] = sred[tid] + sred[tid + 128];
}

// Per layer: reduce BN1 stats -> BN+ReLU -> MLP2 -> h2 + BN2 partial stats
__global__ __launch_bounds__(256) void d_kernel(
    const float* __restrict__ h1, const float* __restrict__ W2,
    const float* __restrict__ b2, const float* __restrict__ g1,
    const float* __restrict__ be1, float* __restrict__ h2,
    const float* __restrict__ p1s, const float* __restrict__ p1q,
    float* __restrict__ p2s, float* __restrict__ p2q) {
  __shared__ float sW2[D2 * DD];      // 32 KB
  __shared__ float sh1[RPB][D2];      // 8 KB
  __shared__ float sS[D2], sB[D2];
  __shared__ float sred[256];
  int tid = threadIdx.x, bid = blockIdx.x;

  for (int i = tid; i < D2 * DD; i += 256) sW2[i] = W2[i];
  {
    int c = tid & 127;
    const float* p = (tid < 128) ? p1s : p1q;
    float s = 0.f;
    for (int g = 0; g < GB; ++g) s += p[g * 128 + c];
    sred[tid] = s;
  }
  __syncthreads();
  if (tid < 128) {
    float mean = sred[tid] * (1.0f / RTOT);
    float var = fmaf(-mean, mean, sred[tid + 128] * (1.0f / RTOT));
    float sc = g1[tid] * rsqrtf(var + 1e-5f);
    sS[tid] = sc;
    sB[tid] = fmaf(-mean, sc, be1[tid]);
  }
  __syncthreads();
  for (int i = tid; i < RPB * D2; i += 256) {
    int lr = i >> 7, c = i & 127;
    float v = h1[(size_t)(bid * RPB + lr) * D2 + c];
    v = fmaf(v, sS[c], sB[c]);
    sh1[lr][c] = fmaxf(v, 0.f);
  }
  __syncthreads();

  int c2 = tid & 63, rl = tid >> 6;
  float bc = b2[c2];
  float ssum = 0.f, sq = 0.f;
  for (int rr = 0; rr < 4; ++rr) {
    int lr = rr * 4 + rl;
    float acc = bc;
#pragma unroll
    for (int c = 0; c < D2; ++c) acc = fmaf(sh1[lr][c], sW2[c * DD + c2], acc);
    h2[(size_t)(bid * RPB + lr) * DD + c2] = acc;
    ssum += acc; sq = fmaf(acc, acc, sq);
  }
  sred[tid] = ssum; __syncthreads();
  if (tid < 64) p2s[bid * 64 + tid] =
      sred[tid] + sred[tid + 64] + sred[tid + 128] + sred[tid + 192];
  __syncthreads();
  sred[tid] = sq; __syncthreads();
  if (tid < 64) p2q[bid * 64 + tid] =
      sred[tid] + sred[tid + 64] + sred[tid + 128] + sred[tid + 192];
}

// Per layer: reduce BN2 stats -> BN (+ReLU except last) elementwise
__global__ __launch_bounds__(256) void e_kernel(
    const float* __restrict__ h2, const float* __restrict__ gbn,
    const float* __restrict__ bbn, const float* __restrict__ p2s,
    const float* __restrict__ p2q, float* __restrict__ outp, int do_relu) {
  __shared__ float sS[DD], sB[DD], sred[128];
  int tid = threadIdx.x, bid = blockIdx.x;
  if (tid < 128) {
    int c = tid & 63;
    const float* p = (tid < 64) ? p2s : p2q;
    float s = 0.f;
    for (int g = 0; g < GB; ++g) s += p[g * 64 + c];
    sred[tid] = s;
  }
  __syncthreads();
  if (tid < 64) {
    float mean = sred[tid] * (1.0f / RTOT);
    float var = fmaf(-mean, mean, sred[tid + 64] * (1.0f / RTOT));
    float sc = gbn[tid] * rsqrtf(var + 1e-5f);
    sS[tid] = sc; sB[tid] = fmaf(-mean, sc, bbn[tid]);
  }
  __syncthreads();
  for (int k = 0; k < 4; ++k) {
    int idx = bid * 1024 + k * 256 + tid;
    int c = idx & 63;
    float v = fmaf(h2[idx], sS[c], sB[c]);
    if (do_relu) v = fmaxf(v, 0.f);
    outp[idx] = v;
  }
}

extern "C" void kernel_launch(void* const* d_in, const int* in_sizes, int n_in,
                              void* d_out, int out_size, void* d_ws, size_t ws_size,
                              hipStream_t stream) {
  const float* fea  = (const float*)d_in[0];
  const float* adj  = (const float*)d_in[1];
  const float* encW = (const float*)d_in[2];
  const float* encb = (const float*)d_in[3];
  const float* bondW= (const float*)d_in[4];
  const float* eps  = (const float*)d_in[5];
  const float* W1   = (const float*)d_in[6];
  const float* b1   = (const float*)d_in[7];
  const float* g1   = (const float*)d_in[8];
  const float* be1  = (const float*)d_in[9];
  const float* W2   = (const float*)d_in[10];
  const float* b2   = (const float*)d_in[11];
  const float* gbn  = (const float*)d_in[12];
  const float* bbn  = (const float*)d_in[13];
  float* out = (float*)d_out;
  float* ws  = (float*)d_ws;

  float* x   = ws;                 // 262144 floats
  float* h1  = ws + 262144;        // 524288 floats
  float* p1s = ws + 786432;        // 32768
  float* p1q = p1s + 32768;        // 32768
  float* p2s = p1q + 32768;        // 16384
  float* p2q = p2s + 16384;        // 16384

  enc_kernel<<<RTOT * DD / 256, 256, 0, stream>>>(fea, encW, encb, x);
  for (int l = 0; l < 3; ++l) {
    bc_kernel<<<GB, 256, 0, stream>>>(adj, x, bondW + l * DD, eps + l,
                                      W1 + l * DD * D2, b1 + l * D2, h1, p1s, p1q);
    d_kernel<<<GB, 256, 0, stream>>>(h1, W2 + l * D2 * DD, b2 + l * DD,
                                     g1 + l * D2, be1 + l * D2, x,
                                     p1s, p1q, p2s, p2q);
    e_kernel<<<GB, 256, 0, stream>>>(x, gbn + l * DD, bbn + l * DD, p2s, p2q,
                                     l == 2 ? out : x, l < 2 ? 1 : 0);
  }
}

// Round 3
// 110.499 us; speedup vs baseline: 2.0323x; 2.0323x over previous
//
#include <hip/hip_runtime.h>

#define BB 16
#define NN 256
#define DIN 32
#define DD 64
#define D2 128
#define RTOT 4096      // BB*NN rows
#define GB 256         // blocks for bc/d/e kernels
#define RPB 16         // rows per block
#define JC 64          // j-chunk for agg

__device__ __forceinline__ void fma4(float4& o, float s, const float4& w) {
  o.x = fmaf(s, w.x, o.x);
  o.y = fmaf(s, w.y, o.y);
  o.z = fmaf(s, w.z, o.z);
  o.w = fmaf(s, w.w, o.w);
}

// x[r,c] = fea[r,:] @ encW + encb
__global__ __launch_bounds__(256) void enc_kernel(
    const float* __restrict__ fea, const float* __restrict__ W,
    const float* __restrict__ bias, float* __restrict__ x) {
  int g = blockIdx.x * 256 + threadIdx.x;   // 0 .. RTOT*DD-1
  int r = g >> 6, c = g & 63;
  const float* fr = fea + r * DIN;
  float acc = bias[c];
#pragma unroll
  for (int k = 0; k < DIN; ++k) acc = fmaf(fr[k], W[k * DD + c], acc);
  x[g] = acc;
}

// Per layer: sparse agg (ballot-compacted, LDS-staged y) -> h -> MLP1 -> h1 + BN1 partials
__global__ __launch_bounds__(256) void bc_kernel(
    const float* __restrict__ adj, const float* __restrict__ x,
    const float* __restrict__ bondW, const float* __restrict__ epsp,
    const float* __restrict__ W1, const float* __restrict__ b1,
    float* __restrict__ h1, float* __restrict__ p1s, float* __restrict__ p1q) {
  __shared__ float sW1[DD * D2];      // 32 KB
  __shared__ float sy[JC][DD];        // 16 KB (reused as psum/psq later)
  __shared__ float sadj[RPB][JC];     // 4 KB
  __shared__ float sh[RPB][DD];       // 4 KB
  __shared__ float sbw[DD];
  int tid = threadIdx.x, bid = blockIdx.x;
  int lane = tid & 63, wv = tid >> 6;
  int b = bid >> 4;            // batch
  int r0 = (bid & 15) * RPB;   // row offset within batch

  for (int i = tid; i < DD * D2; i += 256) sW1[i] = W1[i];
  if (tid < DD) sbw[tid] = bondW[tid];

  const float* xb = x + (size_t)b * NN * DD;
  const float* adjb = adj + ((size_t)b * NN + r0) * NN;

  float acc[4] = {0.f, 0.f, 0.f, 0.f};   // wave's 4 rows: lr = wv*4 + k
  for (int jc = 0; jc < NN; jc += JC) {
    __syncthreads();   // protect sy/sadj from previous readers (also fences sbw/sW1 staging)
    // stage y chunk: relu(x[b, jc+t, d] + bw[d]), 64 rows x 64 d = 1024 float4
    for (int i = tid; i < JC * DD / 4; i += 256) {
      float4 v = ((const float4*)(xb + (size_t)jc * DD))[i];
      int d0 = (i & (DD / 4 - 1)) * 4;
      v.x = fmaxf(v.x + sbw[d0 + 0], 0.f);
      v.y = fmaxf(v.y + sbw[d0 + 1], 0.f);
      v.z = fmaxf(v.z + sbw[d0 + 2], 0.f);
      v.w = fmaxf(v.w + sbw[d0 + 3], 0.f);
      ((float4*)&sy[0][0])[i] = v;
    }
    // stage adj tile: RPB rows x JC cols = 256 float4 (1 per thread)
    {
      int i = tid;
      int lr = i >> 4, c4 = (i & 15) * 4;
      float4 v = *(const float4*)(adjb + (size_t)lr * NN + jc + c4);
      *(float4*)&sadj[lr][c4] = v;
    }
    __syncthreads();
    // ballot-compacted sparse accumulate (adj is binary {0,1})
#pragma unroll
    for (int k = 0; k < 4; ++k) {
      int lr = wv * 4 + k;
      float a = sadj[lr][lane];
      unsigned long long m = __ballot(a != 0.f);
      while (m) {
        int j = __builtin_ctzll(m);
        m &= m - 1;
        acc[k] += sy[j][lane];
      }
    }
  }

  float epv = 1.0f + epsp[0];
#pragma unroll
  for (int k = 0; k < 4; ++k) {
    int lr = wv * 4 + k;
    sh[lr][lane] = fmaf(epv, x[((size_t)b * NN + r0 + lr) * DD + lane], acc[k]);
  }
  __syncthreads();

  // MLP1: 16x128 output tile, thread = 2 rows x 4 cols register tile
  int rg = tid >> 5;          // 8 row-groups (2 rows each)
  int c0 = (tid & 31) * 4;    // 128 cols
  float4 bv = *(const float4*)&b1[c0];
  float4 o0 = bv, o1 = bv;
  for (int d = 0; d < DD; d += 4) {
    float4 s0 = *(const float4*)&sh[rg * 2 + 0][d];
    float4 s1 = *(const float4*)&sh[rg * 2 + 1][d];
    float4 w0 = *(const float4*)&sW1[(d + 0) * D2 + c0];
    float4 w1 = *(const float4*)&sW1[(d + 1) * D2 + c0];
    float4 w2 = *(const float4*)&sW1[(d + 2) * D2 + c0];
    float4 w3 = *(const float4*)&sW1[(d + 3) * D2 + c0];
    fma4(o0, s0.x, w0); fma4(o0, s0.y, w1); fma4(o0, s0.z, w2); fma4(o0, s0.w, w3);
    fma4(o1, s1.x, w0); fma4(o1, s1.y, w1); fma4(o1, s1.z, w2); fma4(o1, s1.w, w3);
  }
  {
    size_t gr = (size_t)(bid * RPB + rg * 2) * D2 + c0;
    *(float4*)&h1[gr] = o0;
    *(float4*)&h1[gr + D2] = o1;
  }
  // BN1 partial stats: per-thread 2-row partial -> LDS (overlay on sy) -> 128-col reduce
  float* psum = &sy[0][0];           // 1024 floats
  float* psq  = &sy[0][0] + 1024;    // 1024 floats
  *(float4*)&psum[rg * D2 + c0] =
      make_float4(o0.x + o1.x, o0.y + o1.y, o0.z + o1.z, o0.w + o1.w);
  *(float4*)&psq[rg * D2 + c0] =
      make_float4(o0.x * o0.x + o1.x * o1.x, o0.y * o0.y + o1.y * o1.y,
                  o0.z * o0.z + o1.z * o1.z, o0.w * o0.w + o1.w * o1.w);
  __syncthreads();
  if (tid < D2) {
    float s = 0.f, q = 0.f;
#pragma unroll
    for (int g = 0; g < 8; ++g) { s += psum[g * D2 + tid]; q += psq[g * D2 + tid]; }
    p1s[bid * D2 + tid] = s;
    p1q[bid * D2 + tid] = q;
  }
}

// Per layer: reduce BN1 stats -> BN+ReLU -> MLP2 (register-tiled) -> h2 + BN2 partials
__global__ __launch_bounds__(256) void d_kernel(
    const float* __restrict__ h1, const float* __restrict__ W2,
    const float* __restrict__ b2, const float* __restrict__ g1,
    const float* __restrict__ be1, float* __restrict__ h2,
    const float* __restrict__ p1s, const float* __restrict__ p1q,
    float* __restrict__ p2s, float* __restrict__ p2q) {
  __shared__ float sW2[D2 * DD];          // 32 KB
  __shared__ float sh1[RPB][D2 + 4];      // padded
  __shared__ float sS[D2], sB[D2];
  __shared__ float sred[256];
  __shared__ float pstat[2][RPB][DD];     // 8 KB
  int tid = threadIdx.x, bid = blockIdx.x;

  for (int i = tid; i < D2 * DD; i += 256) sW2[i] = W2[i];
  {
    int c = tid & 127;
    const float* p = (tid < 128) ? p1s : p1q;
    float s = 0.f;
    for (int g = 0; g < GB; ++g) s += p[g * 128 + c];
    sred[tid] = s;
  }
  __syncthreads();
  if (tid < 128) {
    float mean = sred[tid] * (1.0f / RTOT);
    float var = fmaf(-mean, mean, sred[tid + 128] * (1.0f / RTOT));
    float sc = g1[tid] * rsqrtf(var + 1e-5f);
    sS[tid] = sc;
    sB[tid] = fmaf(-mean, sc, be1[tid]);
  }
  __syncthreads();
  for (int i = tid; i < RPB * D2 / 4; i += 256) {   // 512 float4, 2/thread
    float4 v = ((const float4*)(h1 + (size_t)bid * RPB * D2))[i];
    int lr = i >> 5, c = (i & 31) * 4;
    v.x = fmaxf(fmaf(v.x, sS[c + 0], sB[c + 0]), 0.f);
    v.y = fmaxf(fmaf(v.y, sS[c + 1], sB[c + 1]), 0.f);
    v.z = fmaxf(fmaf(v.z, sS[c + 2], sB[c + 2]), 0.f);
    v.w = fmaxf(fmaf(v.w, sS[c + 3], sB[c + 3]), 0.f);
    *(float4*)&sh1[lr][c] = v;
  }
  __syncthreads();

  // MLP2: 16x64 output tile, thread = 1 row x 4 cols
  int rg = tid >> 4;          // 16 rows
  int c0 = (tid & 15) * 4;    // 64 cols
  float4 o = *(const float4*)&b2[c0];
  for (int c = 0; c < D2; c += 4) {
    float4 s  = *(const float4*)&sh1[rg][c];
    float4 w0 = *(const float4*)&sW2[(c + 0) * DD + c0];
    float4 w1 = *(const float4*)&sW2[(c + 1) * DD + c0];
    float4 w2 = *(const float4*)&sW2[(c + 2) * DD + c0];
    float4 w3 = *(const float4*)&sW2[(c + 3) * DD + c0];
    fma4(o, s.x, w0); fma4(o, s.y, w1); fma4(o, s.z, w2); fma4(o, s.w, w3);
  }
  *(float4*)&h2[(size_t)(bid * RPB + rg) * DD + c0] = o;
  *(float4*)&pstat[0][rg][c0] = o;
  *(float4*)&pstat[1][rg][c0] = make_float4(o.x * o.x, o.y * o.y, o.z * o.z, o.w * o.w);
  __syncthreads();
  if (tid < DD) {
    float s = 0.f, q = 0.f;
#pragma unroll
    for (int g = 0; g < RPB; ++g) { s += pstat[0][g][tid]; q += pstat[1][g][tid]; }
    p2s[bid * DD + tid] = s;
    p2q[bid * DD + tid] = q;
  }
}

// Per layer: reduce BN2 stats -> BN (+ReLU except last) elementwise
__global__ __launch_bounds__(256) void e_kernel(
    const float* __restrict__ h2, const float* __restrict__ gbn,
    const float* __restrict__ bbn, const float* __restrict__ p2s,
    const float* __restrict__ p2q, float* __restrict__ outp, int do_relu) {
  __shared__ float sS[DD], sB[DD], sred[128];
  int tid = threadIdx.x, bid = blockIdx.x;
  if (tid < 128) {
    int c = tid & 63;
    const float* p = (tid < 64) ? p2s : p2q;
    float s = 0.f;
    for (int g = 0; g < GB; ++g) s += p[g * 64 + c];
    sred[tid] = s;
  }
  __syncthreads();
  if (tid < 64) {
    float mean = sred[tid] * (1.0f / RTOT);
    float var = fmaf(-mean, mean, sred[tid + 64] * (1.0f / RTOT));
    float sc = gbn[tid] * rsqrtf(var + 1e-5f);
    sS[tid] = sc; sB[tid] = fmaf(-mean, sc, bbn[tid]);
  }
  __syncthreads();
  for (int k = 0; k < 4; ++k) {
    int idx = bid * 1024 + k * 256 + tid;
    int c = idx & 63;
    float v = fmaf(h2[idx], sS[c], sB[c]);
    if (do_relu) v = fmaxf(v, 0.f);
    outp[idx] = v;
  }
}

extern "C" void kernel_launch(void* const* d_in, const int* in_sizes, int n_in,
                              void* d_out, int out_size, void* d_ws, size_t ws_size,
                              hipStream_t stream) {
  const float* fea  = (const float*)d_in[0];
  const float* adj  = (const float*)d_in[1];
  const float* encW = (const float*)d_in[2];
  const float* encb = (const float*)d_in[3];
  const float* bondW= (const float*)d_in[4];
  const float* eps  = (const float*)d_in[5];
  const float* W1   = (const float*)d_in[6];
  const float* b1   = (const float*)d_in[7];
  const float* g1   = (const float*)d_in[8];
  const float* be1  = (const float*)d_in[9];
  const float* W2   = (const float*)d_in[10];
  const float* b2   = (const float*)d_in[11];
  const float* gbn  = (const float*)d_in[12];
  const float* bbn  = (const float*)d_in[13];
  float* out = (float*)d_out;
  float* ws  = (float*)d_ws;

  float* x   = ws;                 // 262144 floats
  float* h1  = ws + 262144;        // 524288 floats
  float* p1s = ws + 786432;        // 32768
  float* p1q = p1s + 32768;        // 32768
  float* p2s = p1q + 32768;        // 16384
  float* p2q = p2s + 16384;        // 16384

  enc_kernel<<<RTOT * DD / 256, 256, 0, stream>>>(fea, encW, encb, x);
  for (int l = 0; l < 3; ++l) {
    bc_kernel<<<GB, 256, 0, stream>>>(adj, x, bondW + l * DD, eps + l,
                                      W1 + l * DD * D2, b1 + l * D2, h1, p1s, p1q);
    d_kernel<<<GB, 256, 0, stream>>>(h1, W2 + l * D2 * DD, b2 + l * DD,
                                     g1 + l * D2, be1 + l * D2, x,
                                     p1s, p1q, p2s, p2q);
    e_kernel<<<GB, 256, 0, stream>>>(x, gbn + l * DD, bbn + l * DD, p2s, p2q,
                                     l == 2 ? out : x, l < 2 ? 1 : 0);
  }
}